// Round 10
// baseline (3073.186 us; speedup 1.0000x reference)
//
#include <hip/hip_runtime.h>
#include <math.h>

// VanillaRNN, bit-exact (R4-R9 PASS) + R10: relax VGPR budget to evict AGPRs.
//
// Numerics (FROZEN — chaotic recurrence, bitwise match):
//   * z[i] = ascending-k single FMA chain k=0..255, init 0, split across two
//     thread groups in program order (P: k=0..127 -> exact float LDS handoff
//     -> Q: k=128..255) — identical op sequence, bit-exact (R7-R9 passed).
//   * z = ((W_hx*x_t) + chain) + bias_h, separately rounded, left-assoc
//   * tanh = Eigen/XLA fast-tanh WITH FMA (clamp 7.99881172180175781f)
//
// R10 change — why: R7/R8/R9 all show VGPR_Count=80 with 128 live w values
// and VALU-busy ~2270 cyc/step vs ~1172 source => ~1 extra VALU instr per
// fmaf = v_accvgpr_read per w use (w lives in AGPRs under the 256-reg budget
// that launch_bounds(512,2) imposes). hbm_bytes is ~3.3 MB/dispatch (I
// earlier misread units) — no reload traffic; this is pure register-class
// overhead. R6 precedent: at a 512-reg budget (min 1 wave/EU) the compiler
// allocated 208 ARCH VGPRs. So: __launch_bounds__(512, 1). Expected ~200
// arch VGPRs -> no accvgpr traffic; HW occupancy still 2 waves/SIMD
// (usage <= 256), preserving the P/Q latency-covering pair.

#define TT 2048
#define BB 512
#define HH 256
#define CC 10
#define KH 128   // chain half-length per thread group

__device__ __forceinline__ float ref_tanhf(float x)
{
    const float a1  = 4.89352455891786e-03f;
    const float a3  = 6.37261928875436e-04f;
    const float a5  = 1.48572235717979e-05f;
    const float a7  = 5.12229709037114e-08f;
    const float a9  = -8.60467152213735e-11f;
    const float a11 = 2.00018790482477e-13f;
    const float a13 = -2.76076847742355e-16f;
    const float b0  = 4.89352518554385e-03f;
    const float b2  = 2.26843463243900e-03f;
    const float b4  = 1.18534705686654e-04f;
    const float b6  = 1.19825839466702e-06f;

    const float kClamp = 7.99881172180175781f;
    const float xc = fmaxf(fminf(x, kClamp), -kClamp);
    const float x2 = __fmul_rn(xc, xc);
    float p = fmaf(x2, a13, a11);
    p = fmaf(x2, p, a9);
    p = fmaf(x2, p, a7);
    p = fmaf(x2, p, a5);
    p = fmaf(x2, p, a3);
    p = fmaf(x2, p, a1);
    p = __fmul_rn(xc, p);
    float q = fmaf(x2, b6, b4);
    q = fmaf(x2, q, b2);
    q = fmaf(x2, q, b0);
    const float r = __fdiv_rn(p, q);
    return (fabsf(x) < 0.0004f) ? x : r;
}

__global__ __launch_bounds__(512, 1)
void rnn_fwd(const float* __restrict__ x,
             const float* __restrict__ W_hx,
             const float* __restrict__ W_hh,
             const float* __restrict__ W_ph,
             const float* __restrict__ bias_h,
             const float* __restrict__ bias_p,
             float* __restrict__ out)
{
    const int tid   = threadIdx.x;
    const int group = tid >> 8;        // 0 = P (k 0..127), 1 = Q (k 128..255)
    const int i     = tid & (HH - 1);  // hidden row
    const int b0    = blockIdx.x * 2;  // two batch columns per WG

    __shared__ __align__(16) float xls[2][TT];        // 16 KB
    __shared__ __align__(16) float hbuf[2][2][HH];    // [col][parity][row] 4 KB
    __shared__ __align__(16) float zpart[2][HH];      // 2 KB

    // --- stage: this thread's half-row of W_hh -> 128 arch VGPRs ---
    float w[KH];
    const float* __restrict__ wrow = W_hh + (size_t)i * HH + group * KH;
#pragma unroll
    for (int k = 0; k < KH; k += 4) {
        const float4 v = *reinterpret_cast<const float4*>(wrow + k);
        w[k] = v.x; w[k + 1] = v.y; w[k + 2] = v.z; w[k + 3] = v.w;
    }
#pragma unroll
    for (int k = 0; k < KH; ++k) {
        asm volatile("" : "+v"(w[k]));   // pin to arch-VGPR class
    }

    // --- stage: x rows (2*TT contiguous floats) -> LDS, 512 threads ---
    {
        const float4* __restrict__ xsrc =
            reinterpret_cast<const float4*>(x + (size_t)b0 * TT);
        float4* __restrict__ xdst = reinterpret_cast<float4*>(&xls[0][0]);
        xdst[tid]       = xsrc[tid];
        xdst[512 + tid] = xsrc[512 + tid];
    }
    const float whx = W_hx[i];     // used by Q only
    const float bh  = bias_h[i];   // used by Q only

    // h(-1)=0 at parity 1 (step t reads (t&1)^1, writes t&1)
    hbuf[group][1][i] = 0.0f;
    __syncthreads();

// P half-chain: k = 0..127, init 0, store exact partial.
#define PBODY(COL, T, RP)                                                     \
    {                                                                         \
        const float* __restrict__ h = &hbuf[(COL)][(RP)][0];                  \
        float z = 0.0f;                                                       \
        _Pragma("unroll")                                                     \
        for (int k = 0; k < KH; k += 4) {                                     \
            const float4 h4 = *reinterpret_cast<const float4*>(h + k);        \
            z = fmaf(w[k],     h4.x, z);                                      \
            z = fmaf(w[k + 1], h4.y, z);                                      \
            z = fmaf(w[k + 2], h4.z, z);                                      \
            z = fmaf(w[k + 3], h4.w, z);                                      \
        }                                                                     \
        zpart[(COL)][i] = z;                                                  \
    }

// Q half-chain: resume k = 128..255, then x/bias/tanh, write parity RP^1.
#define QBODY(COL, T, RP)                                                     \
    {                                                                         \
        const float* __restrict__ h = &hbuf[(COL)][(RP)][0];                  \
        float z = zpart[(COL)][i];                                            \
        _Pragma("unroll")                                                     \
        for (int k = 0; k < KH; k += 4) {                                     \
            const float4 h4 = *reinterpret_cast<const float4*>(h + KH + k);   \
            z = fmaf(w[k],     h4.x, z);                                      \
            z = fmaf(w[k + 1], h4.y, z);                                      \
            z = fmaf(w[k + 2], h4.z, z);                                      \
            z = fmaf(w[k + 3], h4.w, z);                                      \
        }                                                                     \
        const float a0 = __fmul_rn(whx, xls[(COL)][(T)]);                     \
        z = __fadd_rn(__fadd_rn(a0, z), bh);                                  \
        hbuf[(COL)][(RP) ^ 1][i] = ref_tanhf(z);                              \
    }

// One u-iteration with compile-time read-parity RP = (u&1)^1.
#define STEP(U, RP)                                                           \
    {                                                                         \
        if (group == 0) { PBODY(0, (U), (RP)) }                               \
        else if ((U) >= 1) { QBODY(1, (U) - 1, (RP) ^ 1) }                    \
        __syncthreads();                                                      \
        if (group == 0) { PBODY(1, (U), (RP)) }                               \
        else { QBODY(0, (U), (RP)) }                                          \
        __syncthreads();                                                      \
    }

    // u=0 peeled (resolves the u>=1 guard), then pairs with constant parity.
    STEP(0, 1)
    for (int u = 1; u + 1 < TT; u += 2) {
        STEP(u, 0)
        STEP(u + 1, 1)
    }
    STEP(TT - 1, 0)                       // u = 2047 (odd -> rp = 0)
    if (group == 1) { QBODY(1, TT - 1, 0) }   // drain pipeline: col1, last step
    __syncthreads();

#undef STEP
#undef QBODY
#undef PBODY

    // epilogue: p[b,c] = sum_k h_T[k]*W_ph[c,k] + bias_p[c]
    // last step t = TT-1 wrote parity (TT-1)&1 = 1
    if (tid < 2 * CC) {
        const int col = tid / CC;
        const int c   = tid % CC;
        const float* __restrict__ wp = W_ph + (size_t)c * HH;
        const float* __restrict__ hf = hbuf[col][1];
        float pv = 0.0f;
#pragma unroll 8
        for (int k = 0; k < HH; ++k) {
            pv = fmaf(hf[k], wp[k], pv);
        }
        out[(size_t)(b0 + col) * CC + c] = __fadd_rn(pv, bias_p[c]);
    }
}

extern "C" void kernel_launch(void* const* d_in, const int* in_sizes, int n_in,
                              void* d_out, int out_size, void* d_ws, size_t ws_size,
                              hipStream_t stream) {
    const float* x      = (const float*)d_in[0];
    const float* W_hx   = (const float*)d_in[1];
    const float* W_hh   = (const float*)d_in[2];
    const float* W_ph   = (const float*)d_in[3];
    const float* bias_h = (const float*)d_in[4];
    const float* bias_p = (const float*)d_in[5];
    float* out = (float*)d_out;

    rnn_fwd<<<dim3(BB / 2), dim3(512), 0, stream>>>(x, W_hx, W_hh, W_ph, bias_h, bias_p, out);
}